// Round 8
// baseline (512.480 us; speedup 1.0000x reference)
//
#include <hip/hip_runtime.h>
#include <math.h>

#define Nn 100000
#define Ee 500000
#define Dd 128
#define Rr 10
#define ND (Nn * Dd)
#define EPSF 1e-5f
#define XBLK (ND / 8 / 256)           // 6250 streaming blocks
#define EB ((Ee + 255) / 256)         // 1954 edge blocks (EPT=1)
#define SLOTS 32                      // bin slots per node per direction
#define LDK 136                       // padded LDS row stride (fp16 elems)

typedef _Float16 half_t;
typedef __attribute__((ext_vector_type(2))) _Float16 h2;
typedef __attribute__((ext_vector_type(8))) _Float16 half8;
typedef __attribute__((ext_vector_type(4))) float f32x4;
typedef unsigned short ushort;
typedef unsigned int uint;
typedef unsigned long long u64;

union H8 { uint4 q; _Float16 h[8]; h2 p[4]; };

__device__ __forceinline__ void atomAddF(float* p, float v) {
    unsafeAtomicAdd(p, v);   // HW global_atomic_add_f32
}

// ---------------- zero fill ----------------
__global__ void kzeroi(int* p, int n) {
    int i = blockIdx.x * blockDim.x + threadIdx.x;
    int stride = gridDim.x * blockDim.x;
    for (; i < n; i += stride) p[i] = 0;
}

// ---------------- single-pass bin + W cast + rel chain + rel pads ----------------
// bin record: (nbr<<4)|type, 4B. cnt doubles as degree.
__global__ __launch_bounds__(256) void kbin(
    const int* __restrict__ src, const int* __restrict__ dst,
    const int* __restrict__ typ,
    int* cnt_s, int* cnt_d, uint* __restrict__ rec_s, uint* __restrict__ rec_d,
    const float* __restrict__ w_in, const float* __restrict__ w_out,
    const float* __restrict__ w_loop, const float* __restrict__ w_rel,
    const float* __restrict__ r0,
    half_t* __restrict__ Wt, half_t* __restrict__ rel0p, half_t* __restrict__ rel1p,
    float* __restrict__ r2out) {
    int blk = blockIdx.x;
    int tid = threadIdx.x;
    if (blk < EB) {
        // edge binning, EPT=1 (high block TLP for latency-bound atomics)
        int e = blk * 256 + tid;
        if (e >= Ee) return;
        int s = src[e], d = dst[e], t = typ[e];
        int ps = atomicAdd(&cnt_s[s], 1);
        if (ps < SLOTS) rec_s[((size_t)s << 5) | ps] = (uint)((d << 4) | t);
        int pd = atomicAdd(&cnt_d[d], 1);
        if (pd < SLOTS) rec_d[((size_t)d << 5) | pd] = (uint)((s << 4) | t);
    } else if (blk < EB + 384) {
        // Wt[l][p][n][k] = f16(W[l,p][k][n]) for both layers
        int idx = (blk - EB) * 256 + tid;   // 0..98303
        int l = idx >= 49152;
        int rem = idx - l * 49152;
        int p = rem >> 14, ri = rem & 16383;
        int n = ri >> 7, k = ri & 127;
        const float* W = (p == 0) ? (w_in + l * 16384)
                       : ((p == 1) ? (w_out + l * 16384) : (w_loop + l * 16384));
        Wt[idx] = (half_t)W[k * 128 + n];
    } else if (blk == EB + 384) {
        // rel chain: rel1p = f16(r0 @ w_rel[0]) rows 0..9, pad 10..15 = 0; r2out = r1 @ w_rel[1]
        __shared__ float sr[Rr * Dd];
        for (int i = tid; i < Rr * Dd; i += 256) sr[i] = r0[i];
        __syncthreads();
        for (int ph = 0; ph < 2; ph++) {
            const float* w = w_rel + ph * 16384;
            float o[5];
#pragma unroll
            for (int q = 0; q < 5; q++) {
                int oi = tid + q * 256;
                int row = oi >> 7, j = oi & 127;
                float acc = 0.f;
                for (int k = 0; k < 128; k++) acc += sr[row * 128 + k] * w[k * 128 + j];
                o[q] = acc;
            }
            __syncthreads();
#pragma unroll
            for (int q = 0; q < 5; q++) {
                int oi = tid + q * 256;
                sr[oi] = o[q];
                if (ph == 0) rel1p[oi] = (half_t)o[q];
                else r2out[oi] = o[q];
            }
            __syncthreads();
        }
        for (int i = Rr * Dd + tid; i < 16 * Dd; i += 256) rel1p[i] = (half_t)0.f;
    } else {
        // rel0p: rows 0..9 = f16(r0), rows 10..15 = 0
        for (int i = tid; i < 16 * Dd; i += 256)
            rel0p[i] = (i < Rr * Dd) ? (half_t)r0[i] : (half_t)0.f;
    }
}

// ---------------- pre-scale: xs = f16(x*dinv_s), xd = f16(x*dinv_d), xlb = f16(x*looprel0)
__global__ __launch_bounds__(256) void kscale(
    const float* __restrict__ x, const float* __restrict__ lr0,
    const int* __restrict__ cnt_s, const int* __restrict__ cnt_d,
    half_t* __restrict__ xs, half_t* __restrict__ xd, half_t* __restrict__ xlb) {
    int idx = blockIdx.x * 256 + threadIdx.x;
    int base = idx * 8;
    int k = base & 127;
    int row = base >> 7;
    int cs = cnt_s[row], cd = cnt_d[row];
    float ws = (cs > 0) ? rsqrtf((float)cs) : 0.f;
    float wd = (cd > 0) ? rsqrtf((float)cd) : 0.f;
    float4 v0 = *(const float4*)(x + base);
    float4 v1 = *(const float4*)(x + base + 4);
    float4 l0 = *(const float4*)(lr0 + k);
    float4 l1 = *(const float4*)(lr0 + k + 4);
    float f[8] = {v0.x, v0.y, v0.z, v0.w, v1.x, v1.y, v1.z, v1.w};
    float ll[8] = {l0.x, l0.y, l0.z, l0.w, l1.x, l1.y, l1.z, l1.w};
    H8 a, b, c;
#pragma unroll
    for (int q = 0; q < 8; q++) {
        a.h[q] = (half_t)(f[q] * ws);
        b.h[q] = (half_t)(f[q] * wd);
        c.h[q] = (half_t)(f[q] * ll[q]);
    }
    *(uint4*)(xs + base) = a.q;
    *(uint4*)(xd + base) = b.q;
    *(uint4*)(xlb + base) = c.q;
}

// ---------------- gather v9: whole-bin uint4 record prefetch + 8 independent row loads
__global__ __launch_bounds__(256) void kgather(
    const int* __restrict__ cnt_s, const uint* __restrict__ rec_s,
    const int* __restrict__ cnt_d, const uint* __restrict__ rec_d,
    const half_t* __restrict__ xs, const half_t* __restrict__ xd,
    const half_t* __restrict__ relp,
    half_t* __restrict__ aggin, half_t* __restrict__ aggout, int gb) {
    __shared__ uint4 sRel[256];          // 16 padded type-rows x 128 fp16 = 4 KB
    sRel[threadIdx.x] = ((const uint4*)relp)[threadIdx.x];
    __syncthreads();

    int blk = blockIdx.x;
    const int* cnt; const uint* rec; half_t* agg; const half_t* xsrc;
    if (blk < gb) { cnt = cnt_s; rec = rec_s; agg = aggin; xsrc = xs; }
    else { blk -= gb; cnt = cnt_d; rec = rec_d; agg = aggout; xsrc = xd; }
    int wv = threadIdx.x >> 6;       // wave 0..3
    int lane = threadIdx.x & 63;
    int nq = lane >> 4;              // node quarter 0..3
    int hl = lane & 15;              // 16B chunk within row
    int node = blk * 16 + wv * 4 + nq;   // Nn % 16 == 0: always valid
    int c = cnt[node];
    int n_it = min(c, SLOTS);
    const uint* rp = rec + ((size_t)node << 5);

    const uint4* x16 = (const uint4*)xsrc;
    float accf[8];
#pragma unroll
    for (int k = 0; k < 8; k++) accf[k] = 0.f;

    // first 8 records: one 32B vector fetch (2 x uint4), then 8 INDEPENDENT
    // predicated row loads — ~4x the outstanding loads of the chained loop.
    uint4 ra = *(const uint4*)rp;
    uint4 rb = *(const uint4*)(rp + 4);
    uint r8[8] = {ra.x, ra.y, ra.z, ra.w, rb.x, rb.y, rb.z, rb.w};
    H8 xv[8], rv[8];
#pragma unroll
    for (int it = 0; it < 8; it++) {
        if (it < n_it) {
            xv[it].q = x16[(size_t)(r8[it] >> 4) * 16 + hl];
            rv[it].q = sRel[(r8[it] & 15u) * 16 + hl];
        }
    }
#pragma unroll
    for (int it = 0; it < 8; it++) {
        if (it < n_it) {
#pragma unroll
            for (int k = 0; k < 8; k++)
                accf[k] += (float)xv[it].h[k] * (float)rv[it].h[k];
        }
    }
    // rare tail: deg > 8 (~6% of bins)
    int it = 8;
    for (; it + 1 < n_it; it += 2) {
        uint r0 = rp[it];
        uint r1 = rp[it + 1];
        H8 xv0, xv1, rv0, rv1;
        xv0.q = x16[(size_t)(r0 >> 4) * 16 + hl];
        xv1.q = x16[(size_t)(r1 >> 4) * 16 + hl];
        rv0.q = sRel[(r0 & 15u) * 16 + hl];
        rv1.q = sRel[(r1 & 15u) * 16 + hl];
#pragma unroll
        for (int k = 0; k < 8; k++)
            accf[k] += (float)xv0.h[k] * (float)rv0.h[k];
#pragma unroll
        for (int k = 0; k < 8; k++)
            accf[k] += (float)xv1.h[k] * (float)rv1.h[k];
    }
    if (it < n_it) {
        uint r0 = rp[it];
        H8 xv0, rv0;
        xv0.q = x16[(size_t)(r0 >> 4) * 16 + hl];
        rv0.q = sRel[(r0 & 15u) * 16 + hl];
#pragma unroll
        for (int k = 0; k < 8; k++)
            accf[k] += (float)xv0.h[k] * (float)rv0.h[k];
    }
    {
        float wn = (c > 0) ? rsqrtf((float)c) : 0.f;   // hoisted dinv[row]
        H8 o;
#pragma unroll
        for (int k = 0; k < 8; k++) o.h[k] = (half_t)(accf[k] * wn);
        ((uint4*)agg)[(size_t)node * 16 + hl] = o.q;
    }
}

// ---------------- MFMA GEMM + bias + BN col stats, fp16 out ----------------
__global__ __launch_bounds__(256) void kmm(
    const half_t* __restrict__ aggin, const half_t* __restrict__ aggout,
    const half_t* __restrict__ xlb, const half_t* __restrict__ Wt,
    const float* __restrict__ bias, half_t* __restrict__ out,
    float* colsum, float* colsumsq) {
    __shared__ half_t sW[128 * LDK];
    const int tid = threadIdx.x;
    const int wv = tid >> 6;
    const int lane = tid & 63;
    const int col = lane & 15;
    const int quad = lane >> 4;
    const int m0 = blockIdx.x * 128;
    const int rowbase = m0 + wv * 32;

    f32x4 acc[2][8];
#pragma unroll
    for (int m = 0; m < 2; m++)
#pragma unroll
        for (int j = 0; j < 8; j++) acc[m][j] = (f32x4){0.f, 0.f, 0.f, 0.f};

    const half_t* Ap[3] = {aggin, aggout, xlb};
    int r0 = rowbase + col;
    int r1 = r0 + 16;
    int r0c = (r0 < Nn) ? r0 : (Nn - 1);
    int r1c = (r1 < Nn) ? r1 : (Nn - 1);

    for (int p = 0; p < 3; p++) {
        __syncthreads();
        {
            const half8* Wg = (const half8*)(Wt + p * 16384);
#pragma unroll
            for (int i = 0; i < 8; i++) {
                int c = tid + i * 256;
                int n = c >> 4, ko = (c & 15) * 8;
                *(half8*)(sW + n * LDK + ko) = Wg[c];
            }
        }
        __syncthreads();
        const half_t* A = Ap[p];
#pragma unroll
        for (int s = 0; s < 4; s++) {
            int ko = s * 32 + quad * 8;
            half8 va0 = *(const half8*)(A + r0c * Dd + ko);
            half8 va1 = *(const half8*)(A + r1c * Dd + ko);
#pragma unroll
            for (int j = 0; j < 8; j++) {
                half8 vb = *(const half8*)(sW + (j * 16 + col) * LDK + ko);
                acc[0][j] = __builtin_amdgcn_mfma_f32_16x16x32_f16(va0, vb, acc[0][j], 0, 0, 0);
                acc[1][j] = __builtin_amdgcn_mfma_f32_16x16x32_f16(va1, vb, acc[1][j], 0, 0, 0);
            }
        }
    }

    const float inv3 = 1.f / 3.f;
    float bcol[8], sum[8], ssq[8];
#pragma unroll
    for (int j = 0; j < 8; j++) {
        bcol[j] = bias[j * 16 + col];
        sum[j] = 0.f; ssq[j] = 0.f;
    }
#pragma unroll
    for (int m = 0; m < 2; m++) {
        int rb = rowbase + m * 16;
        if (rb < Nn) {
#pragma unroll
            for (int j = 0; j < 8; j++) {
#pragma unroll
                for (int r = 0; r < 4; r++) {
                    float v = acc[m][j][r] * inv3 + bcol[j];
                    out[(rb + quad * 4 + r) * Dd + j * 16 + col] = (half_t)v;
                    sum[j] += v;
                    ssq[j] += v * v;
                }
            }
        }
    }
#pragma unroll
    for (int j = 0; j < 8; j++) {
        sum[j] += __shfl_xor(sum[j], 16, 64);
        sum[j] += __shfl_xor(sum[j], 32, 64);
        ssq[j] += __shfl_xor(ssq[j], 16, 64);
        ssq[j] += __shfl_xor(ssq[j], 32, 64);
    }
    __syncthreads();
    float* sred = (float*)sW;
    if (quad == 0) {
#pragma unroll
        for (int j = 0; j < 8; j++) {
            sred[wv * 128 + j * 16 + col] = sum[j];
            sred[512 + wv * 128 + j * 16 + col] = ssq[j];
        }
    }
    __syncthreads();
    if (tid < 128) {
        float s = 0.f, s2 = 0.f;
#pragma unroll
        for (int w = 0; w < 4; w++) {
            s += sred[w * 128 + tid];
            s2 += sred[512 + w * 128 + tid];
        }
        atomAddF(&colsum[tid], s);
        atomAddF(&colsumsq[tid], s2);
    }
}

// ---------------- norm+tanh layer0: write xs, xd, xlb for layer 1 ----------------
__global__ __launch_bounds__(256) void knorm0(const half_t* __restrict__ outh,
                                              const float* __restrict__ colsum,
                                              const float* __restrict__ colsumsq,
                                              const float* __restrict__ lr,
                                              const int* __restrict__ cnt_s,
                                              const int* __restrict__ cnt_d,
                                              half_t* __restrict__ xs,
                                              half_t* __restrict__ xd,
                                              half_t* __restrict__ xlb) {
    __shared__ float sm[128], srs[128];
    int tid = threadIdx.x;
    if (tid < 128) {
        float m = colsum[tid] * (1.f / (float)Nn);
        float v = colsumsq[tid] * (1.f / (float)Nn) - m * m;
        sm[tid] = m;
        srs[tid] = rsqrtf(v + EPSF);
    }
    __syncthreads();
    int idx = blockIdx.x * 256 + tid;
    int base = idx * 8;
    int k = base & 127;
    int row = base >> 7;
    int cs = cnt_s[row], cd = cnt_d[row];
    float ws = (cs > 0) ? rsqrtf((float)cs) : 0.f;
    float wd = (cd > 0) ? rsqrtf((float)cd) : 0.f;
    H8 v; v.q = *(const uint4*)(outh + base);
    H8 a, b, c;
#pragma unroll
    for (int q = 0; q < 8; q++) {
        float t = tanhf(((float)v.h[q] - sm[k + q]) * srs[k + q]);
        a.h[q] = (half_t)(t * ws);
        b.h[q] = (half_t)(t * wd);
        c.h[q] = (half_t)(t * lr[k + q]);
    }
    *(uint4*)(xs + base) = a.q;
    *(uint4*)(xd + base) = b.q;
    *(uint4*)(xlb + base) = c.q;
}

// ---------------- norm+tanh layer1 (stats inline): write fp32 final ----------------
__global__ __launch_bounds__(256) void knorm1(const half_t* __restrict__ outh,
                                              const float* __restrict__ colsum,
                                              const float* __restrict__ colsumsq,
                                              float* __restrict__ xn) {
    __shared__ float sm[128], srs[128];
    int tid = threadIdx.x;
    if (tid < 128) {
        float m = colsum[tid] * (1.f / (float)Nn);
        float v = colsumsq[tid] * (1.f / (float)Nn) - m * m;
        sm[tid] = m;
        srs[tid] = rsqrtf(v + EPSF);
    }
    __syncthreads();
    int idx = blockIdx.x * 256 + tid;
    int base = idx * 8;
    int k = base & 127;
    H8 v; v.q = *(const uint4*)(outh + base);
    float4 o0, o1;
    o0.x = tanhf(((float)v.h[0] - sm[k + 0]) * srs[k + 0]);
    o0.y = tanhf(((float)v.h[1] - sm[k + 1]) * srs[k + 1]);
    o0.z = tanhf(((float)v.h[2] - sm[k + 2]) * srs[k + 2]);
    o0.w = tanhf(((float)v.h[3] - sm[k + 3]) * srs[k + 3]);
    o1.x = tanhf(((float)v.h[4] - sm[k + 4]) * srs[k + 4]);
    o1.y = tanhf(((float)v.h[5] - sm[k + 5]) * srs[k + 5]);
    o1.z = tanhf(((float)v.h[6] - sm[k + 6]) * srs[k + 6]);
    o1.w = tanhf(((float)v.h[7] - sm[k + 7]) * srs[k + 7]);
    *(float4*)(xn + base) = o0;
    *(float4*)(xn + base + 4) = o1;
}

extern "C" void kernel_launch(void* const* d_in, const int* in_sizes, int n_in,
                              void* d_out, int out_size, void* d_ws, size_t ws_size,
                              hipStream_t stream) {
    const float* x0      = (const float*)d_in[0];
    const float* r0      = (const float*)d_in[1];
    const float* w_in    = (const float*)d_in[2];
    const float* w_out   = (const float*)d_in[3];
    const float* w_loop  = (const float*)d_in[4];
    const float* w_rel   = (const float*)d_in[5];
    const float* looprel = (const float*)d_in[6];
    const float* bias    = (const float*)d_in[7];
    const int* esrc = (const int*)d_in[8];
    const int* edst = (const int*)d_in[9];
    const int* etyp = (const int*)d_in[10];
    float* outp = (float*)d_out;

    // half region (16B-aligned base)
    half_t* us = (half_t*)d_ws;
    half_t* aggin_h  = us;                        // ND
    half_t* aggout_h = us + (size_t)ND;           // ND
    half_t* xs       = us + 2 * (size_t)ND;       // ND
    half_t* xd       = us + 3 * (size_t)ND;       // ND
    half_t* xlb      = us + 4 * (size_t)ND;       // ND
    half_t* outh     = us + 5 * (size_t)ND;       // ND
    half_t* Wt       = us + 6 * (size_t)ND;       // 2*49152
    half_t* rel0p    = Wt + 2 * 49152;            // 16*128
    half_t* rel1p    = rel0p + 16 * Dd;           // 16*128
    // 4B bin records
    uint* rec_s = (uint*)(rel1p + 16 * Dd);       // Nn*SLOTS
    uint* rec_d = rec_s + (size_t)Nn * SLOTS;     // Nn*SLOTS
    // int region (zero block: cnt_s, cnt_d, colsums A+B contiguous)
    int* cnt_s  = (int*)(rec_d + (size_t)Nn * SLOTS);
    int* cnt_d  = cnt_s + Nn;
    float* colsumA = (float*)(cnt_d + Nn);        // 2*Dd
    float* colsumB = colsumA + 2 * Dd;            // 2*Dd

    // 1: zero cnt_s+cnt_d+colsumA+colsumB
    kzeroi<<<256, 256, 0, stream>>>(cnt_s, 2 * Nn + 4 * Dd);
    // 2: single-pass bin + W cast + rel chain
    kbin<<<EB + 386, 256, 0, stream>>>(
        esrc, edst, etyp, cnt_s, cnt_d, rec_s, rec_d,
        w_in, w_out, w_loop, w_rel, r0,
        Wt, rel0p, rel1p, outp + (size_t)ND);
    // 3: pre-scale x by per-direction dinv (+ self-loop mul)
    kscale<<<XBLK, 256, 0, stream>>>(x0, looprel, cnt_s, cnt_d, xs, xd, xlb);

    const int gb = (Nn + 15) / 16;
    for (int l = 0; l < 2; l++) {
        const half_t* relp = l ? rel1p : rel0p;
        float* cs = l ? colsumB : colsumA;
        kgather<<<2 * gb, 256, 0, stream>>>(cnt_s, rec_s, cnt_d, rec_d,
                                            xs, xd, relp, aggin_h, aggout_h, gb);
        kmm<<<(Nn + 127) / 128, 256, 0, stream>>>(aggin_h, aggout_h, xlb, Wt + l * 49152,
                                                  bias + l * Dd, outh, cs, cs + Dd);
        if (l == 0) {
            knorm0<<<ND / 8 / 256, 256, 0, stream>>>(outh, cs, cs + Dd, looprel + Dd,
                                                     cnt_s, cnt_d, xs, xd, xlb);
        } else {
            knorm1<<<ND / 8 / 256, 256, 0, stream>>>(outh, cs, cs + Dd, outp);
        }
    }
}

// Round 9
// 432.467 us; speedup vs baseline: 1.1850x; 1.1850x over previous
//
#include <hip/hip_runtime.h>
#include <math.h>

#define Nn 100000
#define Ee 500000
#define Dd 128
#define Rr 10
#define ND (Nn * Dd)
#define EPSF 1e-5f
#define XBLK (ND / 8 / 256)           // 6250 streaming blocks
#define EB ((Ee + 255) / 256)         // 1954 edge blocks (EPT=1)
#define SLOTS 32                      // bin slots per node per direction
#define LDK 136                       // padded LDS row stride (fp16 elems)

typedef _Float16 half_t;
typedef __attribute__((ext_vector_type(2))) _Float16 h2;
typedef __attribute__((ext_vector_type(8))) _Float16 half8;
typedef __attribute__((ext_vector_type(4))) float f32x4;
typedef unsigned short ushort;
typedef unsigned int uint;
typedef unsigned long long u64;

union H8 { uint4 q; _Float16 h[8]; h2 p[4]; };

__device__ __forceinline__ void atomAddF(float* p, float v) {
    unsafeAtomicAdd(p, v);   // HW global_atomic_add_f32
}

// ---------------- zero fill ----------------
__global__ void kzeroi(int* p, int n) {
    int i = blockIdx.x * blockDim.x + threadIdx.x;
    int stride = gridDim.x * blockDim.x;
    for (; i < n; i += stride) p[i] = 0;
}

// ---------------- single-pass bin + W cast + rel chain + rel pads ----------------
// bin record: (nbr<<4)|type, 4B. cnt doubles as degree.
__global__ __launch_bounds__(256) void kbin(
    const int* __restrict__ src, const int* __restrict__ dst,
    const int* __restrict__ typ,
    int* cnt_s, int* cnt_d, uint* __restrict__ rec_s, uint* __restrict__ rec_d,
    const float* __restrict__ w_in, const float* __restrict__ w_out,
    const float* __restrict__ w_loop, const float* __restrict__ w_rel,
    const float* __restrict__ r0,
    half_t* __restrict__ Wt, half_t* __restrict__ rel0p, half_t* __restrict__ rel1p,
    float* __restrict__ r2out) {
    int blk = blockIdx.x;
    int tid = threadIdx.x;
    if (blk < EB) {
        // edge binning, EPT=1 (high block TLP for latency-bound atomics)
        int e = blk * 256 + tid;
        if (e >= Ee) return;
        int s = src[e], d = dst[e], t = typ[e];
        int ps = atomicAdd(&cnt_s[s], 1);
        if (ps < SLOTS) rec_s[((size_t)s << 5) | ps] = (uint)((d << 4) | t);
        int pd = atomicAdd(&cnt_d[d], 1);
        if (pd < SLOTS) rec_d[((size_t)d << 5) | pd] = (uint)((s << 4) | t);
    } else if (blk < EB + 384) {
        // Wt[l][p][n][k] = f16(W[l,p][k][n]) for both layers
        int idx = (blk - EB) * 256 + tid;   // 0..98303
        int l = idx >= 49152;
        int rem = idx - l * 49152;
        int p = rem >> 14, ri = rem & 16383;
        int n = ri >> 7, k = ri & 127;
        const float* W = (p == 0) ? (w_in + l * 16384)
                       : ((p == 1) ? (w_out + l * 16384) : (w_loop + l * 16384));
        Wt[idx] = (half_t)W[k * 128 + n];
    } else if (blk == EB + 384) {
        // rel chain: rel1p = f16(r0 @ w_rel[0]) rows 0..9, pad 10..15 = 0; r2out = r1 @ w_rel[1]
        __shared__ float sr[Rr * Dd];
        for (int i = tid; i < Rr * Dd; i += 256) sr[i] = r0[i];
        __syncthreads();
        for (int ph = 0; ph < 2; ph++) {
            const float* w = w_rel + ph * 16384;
            float o[5];
#pragma unroll
            for (int q = 0; q < 5; q++) {
                int oi = tid + q * 256;
                int row = oi >> 7, j = oi & 127;
                float acc = 0.f;
                for (int k = 0; k < 128; k++) acc += sr[row * 128 + k] * w[k * 128 + j];
                o[q] = acc;
            }
            __syncthreads();
#pragma unroll
            for (int q = 0; q < 5; q++) {
                int oi = tid + q * 256;
                sr[oi] = o[q];
                if (ph == 0) rel1p[oi] = (half_t)o[q];
                else r2out[oi] = o[q];
            }
            __syncthreads();
        }
        for (int i = Rr * Dd + tid; i < 16 * Dd; i += 256) rel1p[i] = (half_t)0.f;
    } else {
        // rel0p: rows 0..9 = f16(r0), rows 10..15 = 0
        for (int i = tid; i < 16 * Dd; i += 256)
            rel0p[i] = (i < Rr * Dd) ? (half_t)r0[i] : (half_t)0.f;
    }
}

// ---------------- pre-scale: xs = f16(x*dinv_s), xd = f16(x*dinv_d), xlb = f16(x*looprel0)
__global__ __launch_bounds__(256) void kscale(
    const float* __restrict__ x, const float* __restrict__ lr0,
    const int* __restrict__ cnt_s, const int* __restrict__ cnt_d,
    half_t* __restrict__ xs, half_t* __restrict__ xd, half_t* __restrict__ xlb) {
    int idx = blockIdx.x * 256 + threadIdx.x;
    int base = idx * 8;
    int k = base & 127;
    int row = base >> 7;
    int cs = cnt_s[row], cd = cnt_d[row];
    float ws = (cs > 0) ? rsqrtf((float)cs) : 0.f;
    float wd = (cd > 0) ? rsqrtf((float)cd) : 0.f;
    float4 v0 = *(const float4*)(x + base);
    float4 v1 = *(const float4*)(x + base + 4);
    float4 l0 = *(const float4*)(lr0 + k);
    float4 l1 = *(const float4*)(lr0 + k + 4);
    float f[8] = {v0.x, v0.y, v0.z, v0.w, v1.x, v1.y, v1.z, v1.w};
    float ll[8] = {l0.x, l0.y, l0.z, l0.w, l1.x, l1.y, l1.z, l1.w};
    H8 a, b, c;
#pragma unroll
    for (int q = 0; q < 8; q++) {
        a.h[q] = (half_t)(f[q] * ws);
        b.h[q] = (half_t)(f[q] * wd);
        c.h[q] = (half_t)(f[q] * ll[q]);
    }
    *(uint4*)(xs + base) = a.q;
    *(uint4*)(xd + base) = b.q;
    *(uint4*)(xlb + base) = c.q;
}

// ---------------- gather v10: branch-free 8-wide row-load batch ----------------
// 2 x uint4 fetch the bin's first 8 records; 8 UNGUARDED row loads (index
// clamped for garbage slots); contribution masked with cndmask select.
// Chain depth: rec fetch -> 8 parallel row fetches (2 serial latencies).
__global__ __launch_bounds__(256) void kgather(
    const int* __restrict__ cnt_s, const uint* __restrict__ rec_s,
    const int* __restrict__ cnt_d, const uint* __restrict__ rec_d,
    const half_t* __restrict__ xs, const half_t* __restrict__ xd,
    const half_t* __restrict__ relp,
    half_t* __restrict__ aggin, half_t* __restrict__ aggout, int gb) {
    __shared__ uint4 sRel[256];          // 16 padded type-rows x 128 fp16 = 4 KB
    sRel[threadIdx.x] = ((const uint4*)relp)[threadIdx.x];
    __syncthreads();

    int blk = blockIdx.x;
    const int* cnt; const uint* rec; half_t* agg; const half_t* xsrc;
    if (blk < gb) { cnt = cnt_s; rec = rec_s; agg = aggin; xsrc = xs; }
    else { blk -= gb; cnt = cnt_d; rec = rec_d; agg = aggout; xsrc = xd; }
    int wv = threadIdx.x >> 6;       // wave 0..3
    int lane = threadIdx.x & 63;
    int nq = lane >> 4;              // node quarter 0..3
    int hl = lane & 15;              // 16B chunk within row
    int node = blk * 16 + wv * 4 + nq;   // Nn % 16 == 0: always valid
    int c = cnt[node];
    int n_it = min(c, SLOTS);
    const uint* rp = rec + ((size_t)node << 5);

    const uint4* x16 = (const uint4*)xsrc;
    float accf[8];
#pragma unroll
    for (int k = 0; k < 8; k++) accf[k] = 0.f;

    // whole-bin record fetch: 2 vector loads (one latency for 8 records)
    uint4 ra = *(const uint4*)rp;
    uint4 rb = *(const uint4*)(rp + 4);
    uint r8[8] = {ra.x, ra.y, ra.z, ra.w, rb.x, rb.y, rb.z, rb.w};

    // 8 unguarded, independent row loads (clamped index: garbage-safe)
    H8 xv[8];
#pragma unroll
    for (int it = 0; it < 8; it++) {
        uint nb = r8[it] >> 4;
        nb = (nb < (uint)Nn) ? nb : 0u;
        xv[it].q = x16[(size_t)nb * 16 + hl];
    }
    H8 rv[8];
#pragma unroll
    for (int it = 0; it < 8; it++)
        rv[it].q = sRel[(r8[it] & 15u) * 16 + hl];

    // masked accumulate: cndmask select (NaN-safe, no branches)
#pragma unroll
    for (int it = 0; it < 8; it++) {
        bool ok = it < n_it;
#pragma unroll
        for (int k = 0; k < 8; k++) {
            float prod = (float)xv[it].h[k] * (float)rv[it].h[k];
            accf[k] += ok ? prod : 0.f;
        }
    }

    // rare tail: deg > 8 (~6% of bins), chained loop
    int it = 8;
    for (; it + 1 < n_it; it += 2) {
        uint r0 = rp[it];
        uint r1 = rp[it + 1];
        H8 xv0, xv1, rv0, rv1;
        xv0.q = x16[(size_t)(r0 >> 4) * 16 + hl];
        xv1.q = x16[(size_t)(r1 >> 4) * 16 + hl];
        rv0.q = sRel[(r0 & 15u) * 16 + hl];
        rv1.q = sRel[(r1 & 15u) * 16 + hl];
#pragma unroll
        for (int k = 0; k < 8; k++)
            accf[k] += (float)xv0.h[k] * (float)rv0.h[k];
#pragma unroll
        for (int k = 0; k < 8; k++)
            accf[k] += (float)xv1.h[k] * (float)rv1.h[k];
    }
    if (it < n_it) {
        uint r0 = rp[it];
        H8 xv0, rv0;
        xv0.q = x16[(size_t)(r0 >> 4) * 16 + hl];
        rv0.q = sRel[(r0 & 15u) * 16 + hl];
#pragma unroll
        for (int k = 0; k < 8; k++)
            accf[k] += (float)xv0.h[k] * (float)rv0.h[k];
    }
    {
        float wn = (c > 0) ? rsqrtf((float)c) : 0.f;   // hoisted dinv[row]
        H8 o;
#pragma unroll
        for (int k = 0; k < 8; k++) o.h[k] = (half_t)(accf[k] * wn);
        ((uint4*)agg)[(size_t)node * 16 + hl] = o.q;
    }
}

// ---------------- MFMA GEMM + bias + BN col stats, fp16 out ----------------
__global__ __launch_bounds__(256) void kmm(
    const half_t* __restrict__ aggin, const half_t* __restrict__ aggout,
    const half_t* __restrict__ xlb, const half_t* __restrict__ Wt,
    const float* __restrict__ bias, half_t* __restrict__ out,
    float* colsum, float* colsumsq) {
    __shared__ half_t sW[128 * LDK];
    const int tid = threadIdx.x;
    const int wv = tid >> 6;
    const int lane = tid & 63;
    const int col = lane & 15;
    const int quad = lane >> 4;
    const int m0 = blockIdx.x * 128;
    const int rowbase = m0 + wv * 32;

    f32x4 acc[2][8];
#pragma unroll
    for (int m = 0; m < 2; m++)
#pragma unroll
        for (int j = 0; j < 8; j++) acc[m][j] = (f32x4){0.f, 0.f, 0.f, 0.f};

    const half_t* Ap[3] = {aggin, aggout, xlb};
    int r0 = rowbase + col;
    int r1 = r0 + 16;
    int r0c = (r0 < Nn) ? r0 : (Nn - 1);
    int r1c = (r1 < Nn) ? r1 : (Nn - 1);

    for (int p = 0; p < 3; p++) {
        __syncthreads();
        {
            const half8* Wg = (const half8*)(Wt + p * 16384);
#pragma unroll
            for (int i = 0; i < 8; i++) {
                int c = tid + i * 256;
                int n = c >> 4, ko = (c & 15) * 8;
                *(half8*)(sW + n * LDK + ko) = Wg[c];
            }
        }
        __syncthreads();
        const half_t* A = Ap[p];
#pragma unroll
        for (int s = 0; s < 4; s++) {
            int ko = s * 32 + quad * 8;
            half8 va0 = *(const half8*)(A + r0c * Dd + ko);
            half8 va1 = *(const half8*)(A + r1c * Dd + ko);
#pragma unroll
            for (int j = 0; j < 8; j++) {
                half8 vb = *(const half8*)(sW + (j * 16 + col) * LDK + ko);
                acc[0][j] = __builtin_amdgcn_mfma_f32_16x16x32_f16(va0, vb, acc[0][j], 0, 0, 0);
                acc[1][j] = __builtin_amdgcn_mfma_f32_16x16x32_f16(va1, vb, acc[1][j], 0, 0, 0);
            }
        }
    }

    const float inv3 = 1.f / 3.f;
    float bcol[8], sum[8], ssq[8];
#pragma unroll
    for (int j = 0; j < 8; j++) {
        bcol[j] = bias[j * 16 + col];
        sum[j] = 0.f; ssq[j] = 0.f;
    }
#pragma unroll
    for (int m = 0; m < 2; m++) {
        int rb = rowbase + m * 16;
        if (rb < Nn) {
#pragma unroll
            for (int j = 0; j < 8; j++) {
#pragma unroll
                for (int r = 0; r < 4; r++) {
                    float v = acc[m][j][r] * inv3 + bcol[j];
                    out[(rb + quad * 4 + r) * Dd + j * 16 + col] = (half_t)v;
                    sum[j] += v;
                    ssq[j] += v * v;
                }
            }
        }
    }
#pragma unroll
    for (int j = 0; j < 8; j++) {
        sum[j] += __shfl_xor(sum[j], 16, 64);
        sum[j] += __shfl_xor(sum[j], 32, 64);
        ssq[j] += __shfl_xor(ssq[j], 16, 64);
        ssq[j] += __shfl_xor(ssq[j], 32, 64);
    }
    __syncthreads();
    float* sred = (float*)sW;
    if (quad == 0) {
#pragma unroll
        for (int j = 0; j < 8; j++) {
            sred[wv * 128 + j * 16 + col] = sum[j];
            sred[512 + wv * 128 + j * 16 + col] = ssq[j];
        }
    }
    __syncthreads();
    if (tid < 128) {
        float s = 0.f, s2 = 0.f;
#pragma unroll
        for (int w = 0; w < 4; w++) {
            s += sred[w * 128 + tid];
            s2 += sred[512 + w * 128 + tid];
        }
        atomAddF(&colsum[tid], s);
        atomAddF(&colsumsq[tid], s2);
    }
}

// ---------------- norm+tanh layer0: write xs, xd, xlb for layer 1 ----------------
__global__ __launch_bounds__(256) void knorm0(const half_t* __restrict__ outh,
                                              const float* __restrict__ colsum,
                                              const float* __restrict__ colsumsq,
                                              const float* __restrict__ lr,
                                              const int* __restrict__ cnt_s,
                                              const int* __restrict__ cnt_d,
                                              half_t* __restrict__ xs,
                                              half_t* __restrict__ xd,
                                              half_t* __restrict__ xlb) {
    __shared__ float sm[128], srs[128];
    int tid = threadIdx.x;
    if (tid < 128) {
        float m = colsum[tid] * (1.f / (float)Nn);
        float v = colsumsq[tid] * (1.f / (float)Nn) - m * m;
        sm[tid] = m;
        srs[tid] = rsqrtf(v + EPSF);
    }
    __syncthreads();
    int idx = blockIdx.x * 256 + tid;
    int base = idx * 8;
    int k = base & 127;
    int row = base >> 7;
    int cs = cnt_s[row], cd = cnt_d[row];
    float ws = (cs > 0) ? rsqrtf((float)cs) : 0.f;
    float wd = (cd > 0) ? rsqrtf((float)cd) : 0.f;
    H8 v; v.q = *(const uint4*)(outh + base);
    H8 a, b, c;
#pragma unroll
    for (int q = 0; q < 8; q++) {
        float t = tanhf(((float)v.h[q] - sm[k + q]) * srs[k + q]);
        a.h[q] = (half_t)(t * ws);
        b.h[q] = (half_t)(t * wd);
        c.h[q] = (half_t)(t * lr[k + q]);
    }
    *(uint4*)(xs + base) = a.q;
    *(uint4*)(xd + base) = b.q;
    *(uint4*)(xlb + base) = c.q;
}

// ---------------- norm+tanh layer1 (stats inline): write fp32 final ----------------
__global__ __launch_bounds__(256) void knorm1(const half_t* __restrict__ outh,
                                              const float* __restrict__ colsum,
                                              const float* __restrict__ colsumsq,
                                              float* __restrict__ xn) {
    __shared__ float sm[128], srs[128];
    int tid = threadIdx.x;
    if (tid < 128) {
        float m = colsum[tid] * (1.f / (float)Nn);
        float v = colsumsq[tid] * (1.f / (float)Nn) - m * m;
        sm[tid] = m;
        srs[tid] = rsqrtf(v + EPSF);
    }
    __syncthreads();
    int idx = blockIdx.x * 256 + tid;
    int base = idx * 8;
    int k = base & 127;
    H8 v; v.q = *(const uint4*)(outh + base);
    float4 o0, o1;
    o0.x = tanhf(((float)v.h[0] - sm[k + 0]) * srs[k + 0]);
    o0.y = tanhf(((float)v.h[1] - sm[k + 1]) * srs[k + 1]);
    o0.z = tanhf(((float)v.h[2] - sm[k + 2]) * srs[k + 2]);
    o0.w = tanhf(((float)v.h[3] - sm[k + 3]) * srs[k + 3]);
    o1.x = tanhf(((float)v.h[4] - sm[k + 4]) * srs[k + 4]);
    o1.y = tanhf(((float)v.h[5] - sm[k + 5]) * srs[k + 5]);
    o1.z = tanhf(((float)v.h[6] - sm[k + 6]) * srs[k + 6]);
    o1.w = tanhf(((float)v.h[7] - sm[k + 7]) * srs[k + 7]);
    *(float4*)(xn + base) = o0;
    *(float4*)(xn + base + 4) = o1;
}

extern "C" void kernel_launch(void* const* d_in, const int* in_sizes, int n_in,
                              void* d_out, int out_size, void* d_ws, size_t ws_size,
                              hipStream_t stream) {
    const float* x0      = (const float*)d_in[0];
    const float* r0      = (const float*)d_in[1];
    const float* w_in    = (const float*)d_in[2];
    const float* w_out   = (const float*)d_in[3];
    const float* w_loop  = (const float*)d_in[4];
    const float* w_rel   = (const float*)d_in[5];
    const float* looprel = (const float*)d_in[6];
    const float* bias    = (const float*)d_in[7];
    const int* esrc = (const int*)d_in[8];
    const int* edst = (const int*)d_in[9];
    const int* etyp = (const int*)d_in[10];
    float* outp = (float*)d_out;

    // half region (16B-aligned base)
    half_t* us = (half_t*)d_ws;
    half_t* aggin_h  = us;                        // ND
    half_t* aggout_h = us + (size_t)ND;           // ND
    half_t* xs       = us + 2 * (size_t)ND;       // ND
    half_t* xd       = us + 3 * (size_t)ND;       // ND
    half_t* xlb      = us + 4 * (size_t)ND;       // ND
    half_t* outh     = us + 5 * (size_t)ND;       // ND
    half_t* Wt       = us + 6 * (size_t)ND;       // 2*49152
    half_t* rel0p    = Wt + 2 * 49152;            // 16*128
    half_t* rel1p    = rel0p + 16 * Dd;           // 16*128
    // 4B bin records
    uint* rec_s = (uint*)(rel1p + 16 * Dd);       // Nn*SLOTS
    uint* rec_d = rec_s + (size_t)Nn * SLOTS;     // Nn*SLOTS
    // int region (zero block: cnt_s, cnt_d, colsums A+B contiguous)
    int* cnt_s  = (int*)(rec_d + (size_t)Nn * SLOTS);
    int* cnt_d  = cnt_s + Nn;
    float* colsumA = (float*)(cnt_d + Nn);        // 2*Dd
    float* colsumB = colsumA + 2 * Dd;            // 2*Dd

    // 1: zero cnt_s+cnt_d+colsumA+colsumB
    kzeroi<<<256, 256, 0, stream>>>(cnt_s, 2 * Nn + 4 * Dd);
    // 2: single-pass bin + W cast + rel chain
    kbin<<<EB + 386, 256, 0, stream>>>(
        esrc, edst, etyp, cnt_s, cnt_d, rec_s, rec_d,
        w_in, w_out, w_loop, w_rel, r0,
        Wt, rel0p, rel1p, outp + (size_t)ND);
    // 3: pre-scale x by per-direction dinv (+ self-loop mul)
    kscale<<<XBLK, 256, 0, stream>>>(x0, looprel, cnt_s, cnt_d, xs, xd, xlb);

    const int gb = (Nn + 15) / 16;
    for (int l = 0; l < 2; l++) {
        const half_t* relp = l ? rel1p : rel0p;
        float* cs = l ? colsumB : colsumA;
        kgather<<<2 * gb, 256, 0, stream>>>(cnt_s, rec_s, cnt_d, rec_d,
                                            xs, xd, relp, aggin_h, aggout_h, gb);
        kmm<<<(Nn + 127) / 128, 256, 0, stream>>>(aggin_h, aggout_h, xlb, Wt + l * 49152,
                                                  bias + l * Dd, outh, cs, cs + Dd);
        if (l == 0) {
            knorm0<<<ND / 8 / 256, 256, 0, stream>>>(outh, cs, cs + Dd, looprel + Dd,
                                                     cnt_s, cnt_d, xs, xd, xlb);
        } else {
            knorm1<<<ND / 8 / 256, 256, 0, stream>>>(outh, cs, cs + Dd, outp);
        }
    }
}

// Round 10
// 417.259 us; speedup vs baseline: 1.2282x; 1.0364x over previous
//
#include <hip/hip_runtime.h>
#include <math.h>

#define Nn 100000
#define Ee 500000
#define Dd 128
#define Rr 10
#define ND (Nn * Dd)
#define EPSF 1e-5f
#define XBLK (ND / 8 / 256)           // 6250 streaming blocks
#define EB ((Ee + 255) / 256)         // 1954 edge blocks (EPT=1)
#define SLOTS 32                      // bin slots per node per direction
#define LDK 136                       // padded LDS row stride (fp16 elems)
#define NORMB (ND / 8 / 256)          // 3125 norm streaming blocks

typedef _Float16 half_t;
typedef __attribute__((ext_vector_type(2))) _Float16 h2;
typedef __attribute__((ext_vector_type(8))) _Float16 half8;
typedef __attribute__((ext_vector_type(4))) float f32x4;
typedef unsigned short ushort;
typedef unsigned int uint;
typedef unsigned long long u64;

union H8 { uint4 q; _Float16 h[8]; h2 p[4]; };

__device__ __forceinline__ void atomAddF(float* p, float v) {
    unsafeAtomicAdd(p, v);   // HW global_atomic_add_f32
}

// ---------------- zero fill ----------------
__global__ void kzeroi(int* p, int n) {
    int i = blockIdx.x * blockDim.x + threadIdx.x;
    int stride = gridDim.x * blockDim.x;
    for (; i < n; i += stride) p[i] = 0;
}

// ---------------- PURE edge binning (no freight: W/rel moved to kscale) ----------
// bin record: (nbr<<4)|type, 4B. cnt doubles as degree.
__global__ __launch_bounds__(256) void kbin(
    const int* __restrict__ src, const int* __restrict__ dst,
    const int* __restrict__ typ,
    int* cnt_s, int* cnt_d, uint* __restrict__ rec_s, uint* __restrict__ rec_d) {
    int e = blockIdx.x * 256 + threadIdx.x;
    if (e >= Ee) return;
    int s = src[e], d = dst[e], t = typ[e];
    int ps = atomicAdd(&cnt_s[s], 1);
    if (ps < SLOTS) rec_s[((size_t)s << 5) | ps] = (uint)((d << 4) | t);
    int pd = atomicAdd(&cnt_d[d], 1);
    if (pd < SLOTS) rec_d[((size_t)d << 5) | pd] = (uint)((s << 4) | t);
}

// ---------------- mega-prep/scale: r1 matmul (parallel!) | pads | W cast | x scale ----
// blk 0..4   : r1 = r0 @ w_rel[0] (1280 indep dots, 1/thread) -> r1f fp32 + rel1p f16
// blk 5      : rel0p rows 0..9 = r0, 10..15 = 0; rel1p pad rows 10..15 = 0
// blk 6..389 : Wt[l][p][n][k] = f16(W[l,p][k][n])
// blk 390+   : xs = f16(x*dinv_s), xd = f16(x*dinv_d), xlb = f16(x*looprel0)
__global__ __launch_bounds__(256) void kscale(
    const float* __restrict__ x, const float* __restrict__ lr0,
    const int* __restrict__ cnt_s, const int* __restrict__ cnt_d,
    const float* __restrict__ w_in, const float* __restrict__ w_out,
    const float* __restrict__ w_loop, const float* __restrict__ w_rel,
    const float* __restrict__ r0,
    half_t* __restrict__ xs, half_t* __restrict__ xd, half_t* __restrict__ xlb,
    half_t* __restrict__ Wt, half_t* __restrict__ rel0p, half_t* __restrict__ rel1p,
    float* __restrict__ r1f) {
    int blk = blockIdx.x;
    int tid = threadIdx.x;
    if (blk < 5) {
        int o = blk * 256 + tid;          // [0,1280)
        int row = o >> 7, j = o & 127;
        float acc = 0.f;
        for (int k = 0; k < 128; k++) acc += r0[row * 128 + k] * w_rel[k * 128 + j];
        r1f[o] = acc;
        rel1p[o] = (half_t)acc;
    } else if (blk == 5) {
        for (int i = tid; i < 16 * Dd; i += 256)
            rel0p[i] = (i < Rr * Dd) ? (half_t)r0[i] : (half_t)0.f;
        for (int i = Rr * Dd + tid; i < 16 * Dd; i += 256)
            rel1p[i] = (half_t)0.f;
    } else if (blk < 390) {
        int idx = (blk - 6) * 256 + tid;   // 0..98303
        int l = idx >= 49152;
        int rem = idx - l * 49152;
        int p = rem >> 14, ri = rem & 16383;
        int n = ri >> 7, k = ri & 127;
        const float* W = (p == 0) ? (w_in + l * 16384)
                       : ((p == 1) ? (w_out + l * 16384) : (w_loop + l * 16384));
        Wt[idx] = (half_t)W[k * 128 + n];
    } else {
        int idx = (blk - 390) * 256 + tid;
        int base = idx * 8;
        int k = base & 127;
        int row = base >> 7;
        int cs = cnt_s[row], cd = cnt_d[row];
        float ws = (cs > 0) ? rsqrtf((float)cs) : 0.f;
        float wd = (cd > 0) ? rsqrtf((float)cd) : 0.f;
        float4 v0 = *(const float4*)(x + base);
        float4 v1 = *(const float4*)(x + base + 4);
        float4 l0 = *(const float4*)(lr0 + k);
        float4 l1 = *(const float4*)(lr0 + k + 4);
        float f[8] = {v0.x, v0.y, v0.z, v0.w, v1.x, v1.y, v1.z, v1.w};
        float ll[8] = {l0.x, l0.y, l0.z, l0.w, l1.x, l1.y, l1.z, l1.w};
        H8 a, b, c;
#pragma unroll
        for (int q = 0; q < 8; q++) {
            a.h[q] = (half_t)(f[q] * ws);
            b.h[q] = (half_t)(f[q] * wd);
            c.h[q] = (half_t)(f[q] * ll[q]);
        }
        *(uint4*)(xs + base) = a.q;
        *(uint4*)(xd + base) = b.q;
        *(uint4*)(xlb + base) = c.q;
    }
}

// ---------------- gather v10: branch-free 8-wide row-load batch ----------------
__global__ __launch_bounds__(256) void kgather(
    const int* __restrict__ cnt_s, const uint* __restrict__ rec_s,
    const int* __restrict__ cnt_d, const uint* __restrict__ rec_d,
    const half_t* __restrict__ xs, const half_t* __restrict__ xd,
    const half_t* __restrict__ relp,
    half_t* __restrict__ aggin, half_t* __restrict__ aggout, int gb) {
    __shared__ uint4 sRel[256];          // 16 padded type-rows x 128 fp16 = 4 KB
    sRel[threadIdx.x] = ((const uint4*)relp)[threadIdx.x];
    __syncthreads();

    int blk = blockIdx.x;
    const int* cnt; const uint* rec; half_t* agg; const half_t* xsrc;
    if (blk < gb) { cnt = cnt_s; rec = rec_s; agg = aggin; xsrc = xs; }
    else { blk -= gb; cnt = cnt_d; rec = rec_d; agg = aggout; xsrc = xd; }
    int wv = threadIdx.x >> 6;       // wave 0..3
    int lane = threadIdx.x & 63;
    int nq = lane >> 4;              // node quarter 0..3
    int hl = lane & 15;              // 16B chunk within row
    int node = blk * 16 + wv * 4 + nq;   // Nn % 16 == 0: always valid
    int c = cnt[node];
    int n_it = min(c, SLOTS);
    const uint* rp = rec + ((size_t)node << 5);

    const uint4* x16 = (const uint4*)xsrc;
    float accf[8];
#pragma unroll
    for (int k = 0; k < 8; k++) accf[k] = 0.f;

    // whole-bin record fetch: 2 vector loads (one latency for 8 records)
    uint4 ra = *(const uint4*)rp;
    uint4 rb = *(const uint4*)(rp + 4);
    uint r8[8] = {ra.x, ra.y, ra.z, ra.w, rb.x, rb.y, rb.z, rb.w};

    // 8 unguarded, independent row loads (clamped index: garbage-safe)
    H8 xv[8];
#pragma unroll
    for (int it = 0; it < 8; it++) {
        uint nb = r8[it] >> 4;
        nb = (nb < (uint)Nn) ? nb : 0u;
        xv[it].q = x16[(size_t)nb * 16 + hl];
    }
    H8 rv[8];
#pragma unroll
    for (int it = 0; it < 8; it++)
        rv[it].q = sRel[(r8[it] & 15u) * 16 + hl];

    // masked accumulate: cndmask select (NaN-safe, no branches)
#pragma unroll
    for (int it = 0; it < 8; it++) {
        bool ok = it < n_it;
#pragma unroll
        for (int k = 0; k < 8; k++) {
            float prod = (float)xv[it].h[k] * (float)rv[it].h[k];
            accf[k] += ok ? prod : 0.f;
        }
    }

    // rare tail: deg > 8 (~6% of bins), chained loop
    int it = 8;
    for (; it + 1 < n_it; it += 2) {
        uint r0 = rp[it];
        uint r1 = rp[it + 1];
        H8 xv0, xv1, rv0, rv1;
        xv0.q = x16[(size_t)(r0 >> 4) * 16 + hl];
        xv1.q = x16[(size_t)(r1 >> 4) * 16 + hl];
        rv0.q = sRel[(r0 & 15u) * 16 + hl];
        rv1.q = sRel[(r1 & 15u) * 16 + hl];
#pragma unroll
        for (int k = 0; k < 8; k++)
            accf[k] += (float)xv0.h[k] * (float)rv0.h[k];
#pragma unroll
        for (int k = 0; k < 8; k++)
            accf[k] += (float)xv1.h[k] * (float)rv1.h[k];
    }
    if (it < n_it) {
        uint r0 = rp[it];
        H8 xv0, rv0;
        xv0.q = x16[(size_t)(r0 >> 4) * 16 + hl];
        rv0.q = sRel[(r0 & 15u) * 16 + hl];
#pragma unroll
        for (int k = 0; k < 8; k++)
            accf[k] += (float)xv0.h[k] * (float)rv0.h[k];
    }
    {
        float wn = (c > 0) ? rsqrtf((float)c) : 0.f;   // hoisted dinv[row]
        H8 o;
#pragma unroll
        for (int k = 0; k < 8; k++) o.h[k] = (half_t)(accf[k] * wn);
        ((uint4*)agg)[(size_t)node * 16 + hl] = o.q;
    }
}

// ---------------- MFMA GEMM + bias + BN col stats, fp16 out ----------------
__global__ __launch_bounds__(256) void kmm(
    const half_t* __restrict__ aggin, const half_t* __restrict__ aggout,
    const half_t* __restrict__ xlb, const half_t* __restrict__ Wt,
    const float* __restrict__ bias, half_t* __restrict__ out,
    float* colsum, float* colsumsq) {
    __shared__ half_t sW[128 * LDK];
    const int tid = threadIdx.x;
    const int wv = tid >> 6;
    const int lane = tid & 63;
    const int col = lane & 15;
    const int quad = lane >> 4;
    const int m0 = blockIdx.x * 128;
    const int rowbase = m0 + wv * 32;

    f32x4 acc[2][8];
#pragma unroll
    for (int m = 0; m < 2; m++)
#pragma unroll
        for (int j = 0; j < 8; j++) acc[m][j] = (f32x4){0.f, 0.f, 0.f, 0.f};

    const half_t* Ap[3] = {aggin, aggout, xlb};
    int r0 = rowbase + col;
    int r1 = r0 + 16;
    int r0c = (r0 < Nn) ? r0 : (Nn - 1);
    int r1c = (r1 < Nn) ? r1 : (Nn - 1);

    for (int p = 0; p < 3; p++) {
        __syncthreads();
        {
            const half8* Wg = (const half8*)(Wt + p * 16384);
#pragma unroll
            for (int i = 0; i < 8; i++) {
                int c = tid + i * 256;
                int n = c >> 4, ko = (c & 15) * 8;
                *(half8*)(sW + n * LDK + ko) = Wg[c];
            }
        }
        __syncthreads();
        const half_t* A = Ap[p];
#pragma unroll
        for (int s = 0; s < 4; s++) {
            int ko = s * 32 + quad * 8;
            half8 va0 = *(const half8*)(A + r0c * Dd + ko);
            half8 va1 = *(const half8*)(A + r1c * Dd + ko);
#pragma unroll
            for (int j = 0; j < 8; j++) {
                half8 vb = *(const half8*)(sW + (j * 16 + col) * LDK + ko);
                acc[0][j] = __builtin_amdgcn_mfma_f32_16x16x32_f16(va0, vb, acc[0][j], 0, 0, 0);
                acc[1][j] = __builtin_amdgcn_mfma_f32_16x16x32_f16(va1, vb, acc[1][j], 0, 0, 0);
            }
        }
    }

    const float inv3 = 1.f / 3.f;
    float bcol[8], sum[8], ssq[8];
#pragma unroll
    for (int j = 0; j < 8; j++) {
        bcol[j] = bias[j * 16 + col];
        sum[j] = 0.f; ssq[j] = 0.f;
    }
#pragma unroll
    for (int m = 0; m < 2; m++) {
        int rb = rowbase + m * 16;
        if (rb < Nn) {
#pragma unroll
            for (int j = 0; j < 8; j++) {
#pragma unroll
                for (int r = 0; r < 4; r++) {
                    float v = acc[m][j][r] * inv3 + bcol[j];
                    out[(rb + quad * 4 + r) * Dd + j * 16 + col] = (half_t)v;
                    sum[j] += v;
                    ssq[j] += v * v;
                }
            }
        }
    }
#pragma unroll
    for (int j = 0; j < 8; j++) {
        sum[j] += __shfl_xor(sum[j], 16, 64);
        sum[j] += __shfl_xor(sum[j], 32, 64);
        ssq[j] += __shfl_xor(ssq[j], 16, 64);
        ssq[j] += __shfl_xor(ssq[j], 32, 64);
    }
    __syncthreads();
    float* sred = (float*)sW;
    if (quad == 0) {
#pragma unroll
        for (int j = 0; j < 8; j++) {
            sred[wv * 128 + j * 16 + col] = sum[j];
            sred[512 + wv * 128 + j * 16 + col] = ssq[j];
        }
    }
    __syncthreads();
    if (tid < 128) {
        float s = 0.f, s2 = 0.f;
#pragma unroll
        for (int w = 0; w < 4; w++) {
            s += sred[w * 128 + tid];
            s2 += sred[512 + w * 128 + tid];
        }
        atomAddF(&colsum[tid], s);
        atomAddF(&colsumsq[tid], s2);
    }
}

// ---------------- norm+tanh layer0 (+5 r2-matmul blocks): write xs, xd, xlb ------
__global__ __launch_bounds__(256) void knorm0(const half_t* __restrict__ outh,
                                              const float* __restrict__ colsum,
                                              const float* __restrict__ colsumsq,
                                              const float* __restrict__ lr,
                                              const int* __restrict__ cnt_s,
                                              const int* __restrict__ cnt_d,
                                              half_t* __restrict__ xs,
                                              half_t* __restrict__ xd,
                                              half_t* __restrict__ xlb,
                                              const float* __restrict__ r1f,
                                              const float* __restrict__ w1,
                                              float* __restrict__ r2out) {
    int tid = threadIdx.x;
    if (blockIdx.x >= NORMB) {
        // r2out = r1 @ w_rel[1] (final rel output; 1280 indep dots)
        int o = (blockIdx.x - NORMB) * 256 + tid;   // [0,1280)
        int row = o >> 7, j = o & 127;
        float acc = 0.f;
        for (int k = 0; k < 128; k++) acc += r1f[row * 128 + k] * w1[k * 128 + j];
        r2out[o] = acc;
        return;
    }
    __shared__ float sm[128], srs[128];
    if (tid < 128) {
        float m = colsum[tid] * (1.f / (float)Nn);
        float v = colsumsq[tid] * (1.f / (float)Nn) - m * m;
        sm[tid] = m;
        srs[tid] = rsqrtf(v + EPSF);
    }
    __syncthreads();
    int idx = blockIdx.x * 256 + tid;
    int base = idx * 8;
    int k = base & 127;
    int row = base >> 7;
    int cs = cnt_s[row], cd = cnt_d[row];
    float ws = (cs > 0) ? rsqrtf((float)cs) : 0.f;
    float wd = (cd > 0) ? rsqrtf((float)cd) : 0.f;
    H8 v; v.q = *(const uint4*)(outh + base);
    H8 a, b, c;
#pragma unroll
    for (int q = 0; q < 8; q++) {
        float t = tanhf(((float)v.h[q] - sm[k + q]) * srs[k + q]);
        a.h[q] = (half_t)(t * ws);
        b.h[q] = (half_t)(t * wd);
        c.h[q] = (half_t)(t * lr[k + q]);
    }
    *(uint4*)(xs + base) = a.q;
    *(uint4*)(xd + base) = b.q;
    *(uint4*)(xlb + base) = c.q;
}

// ---------------- norm+tanh layer1 (stats inline): write fp32 final ----------------
__global__ __launch_bounds__(256) void knorm1(const half_t* __restrict__ outh,
                                              const float* __restrict__ colsum,
                                              const float* __restrict__ colsumsq,
                                              float* __restrict__ xn) {
    __shared__ float sm[128], srs[128];
    int tid = threadIdx.x;
    if (tid < 128) {
        float m = colsum[tid] * (1.f / (float)Nn);
        float v = colsumsq[tid] * (1.f / (float)Nn) - m * m;
        sm[tid] = m;
        srs[tid] = rsqrtf(v + EPSF);
    }
    __syncthreads();
    int idx = blockIdx.x * 256 + tid;
    int base = idx * 8;
    int k = base & 127;
    H8 v; v.q = *(const uint4*)(outh + base);
    float4 o0, o1;
    o0.x = tanhf(((float)v.h[0] - sm[k + 0]) * srs[k + 0]);
    o0.y = tanhf(((float)v.h[1] - sm[k + 1]) * srs[k + 1]);
    o0.z = tanhf(((float)v.h[2] - sm[k + 2]) * srs[k + 2]);
    o0.w = tanhf(((float)v.h[3] - sm[k + 3]) * srs[k + 3]);
    o1.x = tanhf(((float)v.h[4] - sm[k + 4]) * srs[k + 4]);
    o1.y = tanhf(((float)v.h[5] - sm[k + 5]) * srs[k + 5]);
    o1.z = tanhf(((float)v.h[6] - sm[k + 6]) * srs[k + 6]);
    o1.w = tanhf(((float)v.h[7] - sm[k + 7]) * srs[k + 7]);
    *(float4*)(xn + base) = o0;
    *(float4*)(xn + base + 4) = o1;
}

extern "C" void kernel_launch(void* const* d_in, const int* in_sizes, int n_in,
                              void* d_out, int out_size, void* d_ws, size_t ws_size,
                              hipStream_t stream) {
    const float* x0      = (const float*)d_in[0];
    const float* r0      = (const float*)d_in[1];
    const float* w_in    = (const float*)d_in[2];
    const float* w_out   = (const float*)d_in[3];
    const float* w_loop  = (const float*)d_in[4];
    const float* w_rel   = (const float*)d_in[5];
    const float* looprel = (const float*)d_in[6];
    const float* bias    = (const float*)d_in[7];
    const int* esrc = (const int*)d_in[8];
    const int* edst = (const int*)d_in[9];
    const int* etyp = (const int*)d_in[10];
    float* outp = (float*)d_out;

    // half region (16B-aligned base)
    half_t* us = (half_t*)d_ws;
    half_t* aggin_h  = us;                        // ND
    half_t* aggout_h = us + (size_t)ND;           // ND
    half_t* xs       = us + 2 * (size_t)ND;       // ND
    half_t* xd       = us + 3 * (size_t)ND;       // ND
    half_t* xlb      = us + 4 * (size_t)ND;       // ND
    half_t* outh     = us + 5 * (size_t)ND;       // ND
    half_t* Wt       = us + 6 * (size_t)ND;       // 2*49152
    half_t* rel0p    = Wt + 2 * 49152;            // 16*128
    half_t* rel1p    = rel0p + 16 * Dd;           // 16*128
    // 4B bin records
    uint* rec_s = (uint*)(rel1p + 16 * Dd);       // Nn*SLOTS
    uint* rec_d = rec_s + (size_t)Nn * SLOTS;     // Nn*SLOTS
    // int region (zero block: cnt_s, cnt_d, colsums A+B contiguous)
    int* cnt_s  = (int*)(rec_d + (size_t)Nn * SLOTS);
    int* cnt_d  = cnt_s + Nn;
    float* colsumA = (float*)(cnt_d + Nn);        // 2*Dd
    float* colsumB = colsumA + 2 * Dd;            // 2*Dd
    float* r1f     = colsumB + 2 * Dd;            // 10*128 fp32 r1 staging

    // 1: zero cnt_s+cnt_d+colsumA+colsumB
    kzeroi<<<256, 256, 0, stream>>>(cnt_s, 2 * Nn + 4 * Dd);
    // 2: PURE edge binning
    kbin<<<EB, 256, 0, stream>>>(esrc, edst, etyp, cnt_s, cnt_d, rec_s, rec_d);
    // 3: r1 matmul (parallel) + pads + W cast + x pre-scale
    kscale<<<390 + XBLK, 256, 0, stream>>>(
        x0, looprel, cnt_s, cnt_d,
        w_in, w_out, w_loop, w_rel, r0,
        xs, xd, xlb, Wt, rel0p, rel1p, r1f);

    const int gb = (Nn + 15) / 16;
    for (int l = 0; l < 2; l++) {
        const half_t* relp = l ? rel1p : rel0p;
        float* cs = l ? colsumB : colsumA;
        kgather<<<2 * gb, 256, 0, stream>>>(cnt_s, rec_s, cnt_d, rec_d,
                                            xs, xd, relp, aggin_h, aggout_h, gb);
        kmm<<<(Nn + 127) / 128, 256, 0, stream>>>(aggin_h, aggout_h, xlb, Wt + l * 49152,
                                                  bias + l * Dd, outh, cs, cs + Dd);
        if (l == 0) {
            knorm0<<<NORMB + 5, 256, 0, stream>>>(outh, cs, cs + Dd, looprel + Dd,
                                                  cnt_s, cnt_d, xs, xd, xlb,
                                                  r1f, w_rel + 16384, outp + (size_t)ND);
        } else {
            knorm1<<<NORMB, 256, 0, stream>>>(outh, cs, cs + Dd, outp);
        }
    }
}